// Round 12
// baseline (252.920 us; speedup 1.0000x reference)
//
#include <hip/hip_runtime.h>
#include <hip/hip_bf16.h>
#include <math.h>

// Problem constants (fixed by setup_inputs)
#define BB 2
#define HH 8
#define LQ 512
#define LK 512
#define DD 32
#define D2 (DD / 2)      // 16 d-pairs
#define C2 2             // d-pairs per LDS chunk (chunk = 4 d's = 16 KB)
#define NC (D2 / C2)     // 8 chunks
#define WAVES 4          // waves per block (256 threads)
#define RPW 4            // q-rows per wave
#define ROWSPB (WAVES * RPW)  // 16 rows per block

#define LOG2E 1.44269504088896f

static __device__ __forceinline__ float fast_rcp(float x) {
#if __has_builtin(__builtin_amdgcn_rcpf)
  return __builtin_amdgcn_rcpf(x);
#else
  return 1.0f / x;
#endif
}

static __device__ __forceinline__ float fast_exp2(float x) {
#if __has_builtin(__builtin_amdgcn_exp2f)
  return __builtin_amdgcn_exp2f(x);
#else
  return __expf(x * 0.69314718056f);
#endif
}

// ---------------------------------------------------------------------------
// Pre-kernel (transposing, d-pair packed):
//   wst4[bh][d2][kk] = {e^-k(2d2), k(2d2)*a(2d2), e^-k(2d2+1), k(2d2+1)*a(2d2+1)}
// ---------------------------------------------------------------------------
__global__ __launch_bounds__(256) void gatv2_prek_p(
    const float* __restrict__ k, const float* __restrict__ att,
    float4* __restrict__ wst4) {
  const int bh = blockIdx.x >> 3;          // 0..15
  const int kt = blockIdx.x & 7;           // kk tile of 64
  const int h = bh & (HH - 1);
  const int t = threadIdx.x;

  __shared__ float tile[64][33];           // +1 pad

  const float4* src = (const float4*)(k + ((size_t)bh * LK + kt * 64) * DD);
#pragma unroll
  for (int i = 0; i < 2; ++i) {
    const int idx = t + i * 256;           // 0..511
    const float4 v = src[idx];
    const int kkl = idx >> 3;
    const int d4 = (idx & 7) * 4;
    tile[kkl][d4 + 0] = v.x; tile[kkl][d4 + 1] = v.y;
    tile[kkl][d4 + 2] = v.z; tile[kkl][d4 + 3] = v.w;
  }
  __syncthreads();

  const int d2 = t >> 4;                   // 0..15
  const int kl0 = (t & 15) * 4;
  const float a0 = att[h * DD + 2 * d2 + 0];
  const float a1 = att[h * DD + 2 * d2 + 1];
  float4* dst = wst4 + ((size_t)bh * D2 + d2) * LK + kt * 64 + kl0;
#pragma unroll
  for (int j = 0; j < 4; ++j) {
    const float k0 = tile[kl0 + j][2 * d2 + 0];
    const float k1 = tile[kl0 + j][2 * d2 + 1];
    float4 o;
    o.x = fast_exp2(-k0 * LOG2E); o.y = k0 * a0;
    o.z = fast_exp2(-k1 * LOG2E); o.w = k1 * a1;
    dst[j] = o;
  }
}

// ---------------------------------------------------------------------------
// Main kernel: 4 waves/block, 4 q-rows per wave (16 rows/block, same bh).
// k-slice staged chunk-wise into double-buffered LDS; each ds_read_b128 is
// reused for FOUR rows. Per (row, 4-elem group): 4-way batched reciprocal:
//   r = rcp(u0*u1*u2*u3); 1/u_i recovered with 2 muls each.
// ---------------------------------------------------------------------------
__global__ __launch_bounds__(256) void gatv2_main_r4(
    const float* __restrict__ q, const int* __restrict__ mask,
    const float* __restrict__ bias, const float* __restrict__ att,
    const float4* __restrict__ wst4, float* __restrict__ out) {
  const int lane = threadIdx.x & 63;
  const int wid = threadIdx.x >> 6;        // 0..3
  const int tid = threadIdx.x;             // 0..255
  const int rowbase = blockIdx.x * ROWSPB; // multiple of 16 -> same bh
  const int bh = rowbase >> 9;
  const int b = rowbase >> 12;
  const int h = bh & (HH - 1);

  __shared__ float4 lds4[2][C2 * LK];      // 2 x 16 KB data
  __shared__ float2 cst2[ROWSPB][DD];      // 4 KB row constants {Eq, q*a}

  const float4* __restrict__ kb = wst4 + (size_t)bh * (D2 * LK);

  // stage chunk 0 (global -> reg), 4 float4 per thread
  float4 s0 = kb[tid];
  float4 s1 = kb[tid + 256];
  float4 s2 = kb[tid + 512];
  float4 s3 = kb[tid + 768];

  // row constants: 512 entries, 2 per thread
#pragma unroll
  for (int i = 0; i < 2; ++i) {
    const int idx = tid + i * 256;         // 0..511
    const int rw = idx >> 5;               // 0..15
    const int d = idx & 31;
    const float qd = q[(size_t)(rowbase + rw) * DD + d];
    const float ad = att[h * DD + d];
    float2 c;
    c.x = fast_exp2(-qd * LOG2E);          // e^{-q_d}
    c.y = qd * ad;                         // q_d * a_d
    cst2[rw][d] = c;
  }
  lds4[0][tid] = s0;
  lds4[0][tid + 256] = s1;
  lds4[0][tid + 512] = s2;
  lds4[0][tid + 768] = s3;

  float acc[RPW][8];
#pragma unroll
  for (int j = 0; j < RPW; ++j)
#pragma unroll
    for (int c = 0; c < 8; ++c) acc[j][c] = 0.0f;

#pragma unroll
  for (int cc = 0; cc < NC; ++cc) {
    __syncthreads();                       // chunk cc staged by all threads

    if (cc + 1 < NC) {                     // issue next-chunk loads early
      const float4* src = kb + (size_t)(cc + 1) * (C2 * LK);
      s0 = src[tid];
      s1 = src[tid + 256];
      s2 = src[tid + 512];
      s3 = src[tid + 768];
    }

    // wave-uniform constants: 4 rows x this chunk's 4 d's ({Eq,qa} x2 pairs)
    float4 cA[RPW], cB[RPW];
#pragma unroll
    for (int j = 0; j < RPW; ++j) {
      const float2* crow = cst2[wid * RPW + j];
      cA[j] = *(const float4*)(crow + 4 * cc);      // d = 4cc, 4cc+1
      cB[j] = *(const float4*)(crow + 4 * cc + 2);  // d = 4cc+2, 4cc+3
    }

    const float4* __restrict__ buf = lds4[cc & 1];
#pragma unroll
    for (int c = 0; c < 8; ++c) {
      const float4 p0 = buf[lane + 64 * c];        // d-pair A {Ek,ka,Ek,ka}
      const float4 p1 = buf[LK + lane + 64 * c];   // d-pair B
#pragma unroll
      for (int j = 0; j < RPW; ++j) {
        const float u0 = fmaf(cA[j].x, p0.x, 1.0f);
        const float u1 = fmaf(cA[j].z, p0.z, 1.0f);
        const float u2 = fmaf(cB[j].x, p1.x, 1.0f);
        const float u3 = fmaf(cB[j].z, p1.z, 1.0f);
        const float t0 = cA[j].y + p0.y;
        const float t1 = cA[j].w + p0.w;
        const float t2 = cB[j].y + p1.y;
        const float t3 = cB[j].w + p1.w;
        const float m01 = u0 * u1;
        const float m23 = u2 * u3;
        const float r = fast_rcp(m01 * m23);       // 1 rcp per 4 elements
        const float r01 = r * m23;                 // ~1/(u0*u1)
        const float r23 = r * m01;                 // ~1/(u2*u3)
        float a = acc[j][c];
        a = fmaf(t0, r01 * u1, a);
        a = fmaf(t1, r01 * u0, a);
        a = fmaf(t2, r23 * u3, a);
        a = fmaf(t3, r23 * u2, a);
        acc[j][c] = a;
      }
    }

    if (cc + 1 < NC) {                     // write next chunk after compute
      float4* dst = lds4[(cc + 1) & 1];
      dst[tid] = s0;
      dst[tid + 256] = s1;
      dst[tid + 512] = s2;
      dst[tid + 768] = s3;
    }
  }

  // --- epilogue: per-row bias+mask, masked softmax, store ---
#pragma unroll
  for (int j = 0; j < RPW; ++j) {
    const int r = rowbase + wid * RPW + j;
    const int qi = r & (LQ - 1);
    const float* __restrict__ brow = bias + (size_t)r * LK;
    const int* __restrict__ mrow = mask + ((size_t)(b * LQ + qi)) * LK;

    float sc[8];
#pragma unroll
    for (int c = 0; c < 8; ++c) {
      const float bval = brow[lane + 64 * c];
      const int mval = mrow[lane + 64 * c];
      sc[c] = mval ? -INFINITY : (acc[j][c] + bval);
    }

    float m = sc[0];
#pragma unroll
    for (int c = 1; c < 8; ++c) m = fmaxf(m, sc[c]);
#pragma unroll
    for (int off = 32; off > 0; off >>= 1)
      m = fmaxf(m, __shfl_xor(m, off, 64));

    float sum = 0.0f;
#pragma unroll
    for (int c = 0; c < 8; ++c) {
      const float p = fast_exp2((sc[c] - m) * LOG2E);
      sc[c] = p;
      sum += p;
    }
#pragma unroll
    for (int off = 32; off > 0; off >>= 1)
      sum += __shfl_xor(sum, off, 64);

    const bool dead = (m == -INFINITY);
    const float inv = dead ? 0.0f : fast_rcp(sum);

    float* __restrict__ orow = out + (size_t)r * LK;
#pragma unroll
    for (int c = 0; c < 8; ++c) {
      orow[lane + 64 * c] = dead ? 0.0f : sc[c] * inv;
    }
  }
}

// ---------------------------------------------------------------------------
// Fallback (proven R2 kernel) in case ws_size < 2 MB.
// ---------------------------------------------------------------------------
__global__ __launch_bounds__(256) void gatv2_fallback(
    const float* __restrict__ q, const float* __restrict__ k,
    const int* __restrict__ mask, const float* __restrict__ bias,
    const float* __restrict__ att, float* __restrict__ out) {
  const int lane = threadIdx.x & 63;
  const int wid = threadIdx.x >> 6;
  const int r = blockIdx.x * 4 + wid;
  const int b = r >> 12;
  const int h = (r >> 9) & (HH - 1);
  const int qi = r & (LQ - 1);

  const float* __restrict__ qrow = q + (size_t)r * DD;
  const float* __restrict__ kbase = k + ((size_t)(b * HH + h)) * (size_t)(LK * DD);
  const float* __restrict__ arow = att + h * DD;
  const float* __restrict__ brow = bias + (size_t)r * LK;
  const int* __restrict__ mrow = mask + ((size_t)(b * LQ + qi)) * LK;

  float qv[DD], av[DD];
#pragma unroll
  for (int d0 = 0; d0 < DD; d0 += 4) {
    const float4 qq = *(const float4*)(qrow + d0);
    const float4 aa = *(const float4*)(arow + d0);
    qv[d0 + 0] = qq.x; qv[d0 + 1] = qq.y; qv[d0 + 2] = qq.z; qv[d0 + 3] = qq.w;
    av[d0 + 0] = aa.x; av[d0 + 1] = aa.y; av[d0 + 2] = aa.z; av[d0 + 3] = aa.w;
  }

  float sc[8];
#pragma unroll
  for (int c = 0; c < 8; ++c) {
    const int kk = lane + 64 * c;
    const float* __restrict__ kr = kbase + (size_t)kk * DD;
    const float bval = brow[kk];
    const int mval = mrow[kk];
    float acc = 0.0f;
#pragma unroll
    for (int d0 = 0; d0 < DD; d0 += 4) {
      const float4 kv = *(const float4*)(kr + d0);
      const float kvf[4] = {kv.x, kv.y, kv.z, kv.w};
#pragma unroll
      for (int j = 0; j < 4; ++j) {
        const float t = qv[d0 + j] + kvf[j];
        const float e = fast_exp2(t * -LOG2E);
        const float sg = fast_rcp(1.0f + e);
        acc = fmaf(t * sg, av[d0 + j], acc);
      }
    }
    const float s = acc + bval;
    sc[c] = mval ? -INFINITY : s;
  }

  float m = sc[0];
#pragma unroll
  for (int c = 1; c < 8; ++c) m = fmaxf(m, sc[c]);
#pragma unroll
  for (int off = 32; off > 0; off >>= 1)
    m = fmaxf(m, __shfl_xor(m, off, 64));

  float sum = 0.0f;
#pragma unroll
  for (int c = 0; c < 8; ++c) {
    const float p = fast_exp2((sc[c] - m) * LOG2E);
    sc[c] = p;
    sum += p;
  }
#pragma unroll
  for (int off = 32; off > 0; off >>= 1)
    sum += __shfl_xor(sum, off, 64);

  const bool dead = (m == -INFINITY);
  const float inv = dead ? 0.0f : fast_rcp(sum);

  float* __restrict__ orow = out + (size_t)r * LK;
#pragma unroll
  for (int c = 0; c < 8; ++c) {
    orow[lane + 64 * c] = dead ? 0.0f : sc[c] * inv;
  }
}

extern "C" void kernel_launch(void* const* d_in, const int* in_sizes, int n_in,
                              void* d_out, int out_size, void* d_ws, size_t ws_size,
                              hipStream_t stream) {
  const float* q = (const float*)d_in[0];
  const float* k = (const float*)d_in[1];
  // d_in[2] = scale, unused
  const int* mask = (const int*)d_in[3];
  const float* bias = (const float*)d_in[4];
  const float* att = (const float*)d_in[5];
  float* out = (float*)d_out;

  const int rows = BB * HH * LQ;                          // 8192
  const size_t ws_needed = (size_t)BB * HH * D2 * LK * sizeof(float4);  // 2 MB

  if (ws_size >= ws_needed) {
    float4* wst4 = (float4*)d_ws;
    gatv2_prek_p<<<dim3(128), dim3(256), 0, stream>>>(k, att, wst4);
    gatv2_main_r4<<<dim3(rows / ROWSPB), dim3(64 * WAVES), 0, stream>>>(
        q, mask, bias, att, wst4, out);
  } else {
    gatv2_fallback<<<dim3(rows / 4), dim3(256), 0, stream>>>(q, k, mask, bias, att, out);
  }
}